// Round 3
// baseline (3083.646 us; speedup 1.0000x reference)
//
#include <hip/hip_runtime.h>

// RSLDS forward pipeline for MI355X (gfx950).
// B=16 T=1000 N=32 K=H=8 R=128 IN=256. Output: 4 f32 scalars
// (Y_prob, init_prob, seq_prob, gamma_prior_prob).

constexpr int B_  = 16;
constexpr int T_  = 1000;
constexpr int N_  = 32;
constexpr int K_  = 8;
constexpr int R_  = 128;
constexpr int IN_ = 256;
constexpr int G3_ = 3 * R_;   // 384

typedef float f32x2 __attribute__((ext_vector_type(2)));
#define PKFMA(w, x, acc) __builtin_elementwise_fma((w), (x), (acc))

// ---------------- helpers ----------------
__device__ __forceinline__ float bmax8(float x){
  x = fmaxf(x, __shfl_xor(x, 1));
  x = fmaxf(x, __shfl_xor(x, 2));
  x = fmaxf(x, __shfl_xor(x, 4));
  return x;
}
__device__ __forceinline__ float bsum8(float x){
  x += __shfl_xor(x, 1);
  x += __shfl_xor(x, 2);
  x += __shfl_xor(x, 4);
  return x;
}
// temp arrives as a 1-element array; robust to int32 or float32 encoding.
__device__ __forceinline__ float decode_scalar(const void* p){
  int iv = *(const int*)p;
  if (iv > -1000000 && iv < 1000000) return (float)iv;
  return *(const float*)p;
}

// ---------------- U = (U_raw * U_scale) @ C_syn^T : (B,T,N) ----------------
// grid 2000, block 256 (8 bt rows per block)
__global__ void u_kernel(const float* __restrict__ U_raw, const float* __restrict__ U_scale,
                         const float* __restrict__ C_syn, float* __restrict__ U){
  __shared__ float us[8][IN_];
  int tid = threadIdx.x;
  int bt0 = blockIdx.x * 8;
  #pragma unroll
  for (int p = 0; p < 8; ++p)
    us[p][tid] = U_raw[(size_t)(bt0 + p) * IN_ + tid] * U_scale[tid];
  __syncthreads();
  int n = tid >> 3, lane = tid & 7;
  float acc[8] = {0.f,0.f,0.f,0.f,0.f,0.f,0.f,0.f};
  for (int c = lane; c < IN_; c += 8){
    float cs = C_syn[n * IN_ + c];
    #pragma unroll
    for (int p = 0; p < 8; ++p) acc[p] += cs * us[p][c];
  }
  #pragma unroll
  for (int p = 0; p < 8; ++p){
    float v = bsum8(acc[p]);
    if (lane == 0) U[(bt0 + p) * N_ + n] = v;
  }
}

// ---------------- gi = enc_in @ Wih^T + bih for both dirs : (T,B,384) ----------------
// grid 250, block 384 (64 bt rows per block, weights register-stationary)
__global__ void gi_kernel(const float* __restrict__ Y, const float* __restrict__ U,
                          const float* __restrict__ WihF, const float* __restrict__ bihF,
                          const float* __restrict__ WihB, const float* __restrict__ bihB,
                          float* __restrict__ giF, float* __restrict__ giB){
  int i = threadIdx.x;
  float wf[N_ + 1], wb[N_ + 1];
  #pragma unroll
  for (int c = 0; c < N_ + 1; ++c){
    wf[c] = WihF[i * (N_ + 1) + c];
    wb[c] = WihB[i * (N_ + 1) + c];
  }
  float bf = bihF[i], bb = bihB[i];
  __shared__ float e[N_ + 1];
  for (int it = 0; it < 64; ++it){
    int bt = blockIdx.x * 64 + it;
    int b = bt / T_, t = bt % T_;
    __syncthreads();
    if (i < N_) e[1 + i] = U[bt * N_ + i];
    if (i == N_) e[0] = Y[bt];
    __syncthreads();
    float af = bf, ab = bb;
    #pragma unroll
    for (int c = 0; c < N_ + 1; ++c){ float ev = e[c]; af += ev * wf[c]; ab += ev * wb[c]; }
    int o = (t * B_ + b) * G3_ + i;
    giF[o] = af; giB[o] = ab;
  }
}

// ---------------- bidirectional GRU, persistent: 32 blocks = (dir,b) ----------------
// thread i = gh row; Whh row in 64 f32x2 VGPR pairs; h (128) and gh (384) in LDS.
// Matvec uses packed v_pk_fma_f32 (2 FLOP/lane/inst). gi for step t+1 is
// register-prefetched during step t's gate phase so L2/L3 latency hides
// under the next matvec phase.
__global__ __launch_bounds__(G3_, 1)
void gru_kernel(const float* __restrict__ WhhF, const float* __restrict__ bhhF,
                const float* __restrict__ WhhB, const float* __restrict__ bhhB,
                const float* __restrict__ giF, const float* __restrict__ giB,
                float* __restrict__ ht){
  int id = blockIdx.x;
  int dir = id >> 4, b = id & 15;
  const float* Whh = dir ? WhhB : WhhF;
  const float* bhh = dir ? bhhB : bhhF;
  const float* gi  = dir ? giB  : giF;
  int i = threadIdx.x;
  f32x2 w2[64];
  const f32x2* wr = (const f32x2*)(Whh + (size_t)i * R_);
  #pragma unroll
  for (int c = 0; c < 64; ++c) w2[c] = wr[c];
  float bh = bhh[i];
  __shared__ __align__(16) float hsh[R_];
  __shared__ float ghsh[G3_];
  if (i < R_) hsh[i] = 0.f;
  // prefetch gi for the first step
  float pr = 0.f, pz = 0.f, pn = 0.f;
  if (i < R_){
    int base0 = ((dir ? T_ - 1 : 0) * B_ + b) * G3_;
    pr = gi[base0 + i];
    pz = gi[base0 + R_ + i];
    pn = gi[base0 + 2 * R_ + i];
  }
  __syncthreads();
  for (int s = 0; s < T_; ++s){
    int t = dir ? (T_ - 1 - s) : s;
    const float4* h4 = (const float4*)hsh;
    f32x2 a0 = {0.f, 0.f}, a1 = {0.f, 0.f}, a2 = {0.f, 0.f}, a3 = {0.f, 0.f};
    #pragma unroll
    for (int c = 0; c < 16; ++c){
      float4 ha = h4[2 * c], hb = h4[2 * c + 1];
      f32x2 p0 = {ha.x, ha.y}, p1 = {ha.z, ha.w};
      f32x2 p2 = {hb.x, hb.y}, p3 = {hb.z, hb.w};
      a0 = PKFMA(w2[4 * c + 0], p0, a0);
      a1 = PKFMA(w2[4 * c + 1], p1, a1);
      a2 = PKFMA(w2[4 * c + 2], p2, a2);
      a3 = PKFMA(w2[4 * c + 3], p3, a3);
    }
    ghsh[i] = bh + ((a0.x + a0.y) + (a1.x + a1.y)) + ((a2.x + a2.y) + (a3.x + a3.y));
    __syncthreads();
    if (i < R_){
      float gir = pr, giz = pz, gin = pn;
      // issue prefetch for next step (completes during next matvec phase)
      int sn = (s < T_ - 1) ? s + 1 : s;
      int tn = dir ? (T_ - 1 - sn) : sn;
      int basen = (tn * B_ + b) * G3_;
      pr = gi[basen + i];
      pz = gi[basen + R_ + i];
      pn = gi[basen + 2 * R_ + i];
      float hr = ghsh[i], hz = ghsh[R_ + i], hn = ghsh[2 * R_ + i];
      float h  = hsh[i];
      float r  = 1.f / (1.f + __expf(-(gir + hr)));
      float z  = 1.f / (1.f + __expf(-(giz + hz)));
      float e2 = __expf(2.f * (gin + r * hn));
      float nn = 1.f - 2.f / (e2 + 1.f);   // tanh, saturation-safe
      float hN = (1.f - z) * nn + z * h;
      hsh[i] = hN;
      ht[(size_t)(t * B_ + b) * 256 + dir * R_ + i] = hN;
    }
    __syncthreads();
  }
}

// ---------------- X = h @ enc_W^T + enc_b : (B,T,256) ----------------
// grid 2000, block 256 (8 bt rows per block)
__global__ void x_kernel(const float* __restrict__ ht, const float* __restrict__ encW,
                         const float* __restrict__ encb, float* __restrict__ X){
  __shared__ __align__(16) float hs[8][256];
  int tid = threadIdx.x;
  int bt0 = blockIdx.x * 8;
  #pragma unroll
  for (int p = 0; p < 8; ++p){
    int bt = bt0 + p;
    int b = bt / T_, t = bt % T_;
    hs[p][tid] = ht[(size_t)(t * B_ + b) * 256 + tid];
  }
  __syncthreads();
  float acc[8] = {0.f,0.f,0.f,0.f,0.f,0.f,0.f,0.f};
  const float4* w4 = (const float4*)(encW + (size_t)tid * 256);
  for (int c4 = 0; c4 < 64; ++c4){
    float4 wv = w4[c4];
    #pragma unroll
    for (int p = 0; p < 8; ++p){
      float4 hv = *(const float4*)&hs[p][c4 * 4];
      acc[p] += wv.x * hv.x + wv.y * hv.y + wv.z * hv.z + wv.w * hv.w;
    }
  }
  float eb = encb[tid];
  #pragma unroll
  for (int p = 0; p < 8; ++p)
    X[(size_t)(bt0 + p) * 256 + tid] = acc[p] + eb;
}

// ---------------- log_B : (B,T,N,K) ----------------
// grid (40,16), block 256; thread = (n,k), 25 t per block, weights in VGPRs.
__global__ __launch_bounds__(256, 2)
void logB_kernel(const float* __restrict__ X, const float* __restrict__ U,
                 const float* __restrict__ Wxx, const float* __restrict__ Wxu,
                 const float* __restrict__ bx, float* __restrict__ logB){
  int b  = blockIdx.y;
  int t0 = blockIdx.x * 25;
  int tid = threadIdx.x;
  int n = tid >> 3, k = tid & 7;
  int wb = (n * K_ + k) * 64;
  float wxx[64];
  #pragma unroll
  for (int c = 0; c < 64; ++c) wxx[c] = Wxx[wb + c];
  float wxu[8], bxr[8];
  #pragma unroll
  for (int h = 0; h < 8; ++h){
    wxu[h] = Wxu[(n * K_ + k) * 8 + h];
    bxr[h] = bx [(n * K_ + k) * 8 + h];
  }
  for (int t = t0; t < t0 + 25; ++t){
    int bt = b * T_ + t;
    const float* xrow = X + (size_t)bt * 256 + n * 8;
    float xo[8], xc[8];
    #pragma unroll
    for (int h = 0; h < 8; ++h) xc[h] = xrow[h];
    if (t > 0){
      #pragma unroll
      for (int h = 0; h < 8; ++h) xo[h] = xrow[h - 256];
    } else {
      #pragma unroll
      for (int h = 0; h < 8; ++h) xo[h] = 0.f;
    }
    float u = U[bt * N_ + n];
    float s = 0.f;
    #pragma unroll
    for (int h = 0; h < 8; ++h){
      float xe = xo[h] + wxu[h] * u + bxr[h];
      #pragma unroll
      for (int j = 0; j < 8; ++j) xe += wxx[h * 8 + j] * xo[j];
      float d = xe - xc[h];
      s += d * d;
    }
    logB[(size_t)bt * 256 + tid] = -s;
  }
}

// log_A row k=q (max-subtraction form, used by final_kernel):
// a[j] = la[b,t,n,q,j], normalized over k (cross-lane) after temp scaling.
__device__ __forceinline__ void la_row_reg(const float (&wz)[64], const float (&wxu)[8],
                                           const float (&bxr)[8], const float (&xp)[8],
                                           float u, float itemp, float (&a)[8]){
  #pragma unroll
  for (int j = 0; j < 8; ++j){
    float x = bxr[j] + wxu[j] * u;
    #pragma unroll
    for (int h = 0; h < 8; ++h) x += wz[j * 8 + h] * xp[h];
    a[j] = x * itemp;
  }
  #pragma unroll
  for (int j = 0; j < 8; ++j){
    float mj = bmax8(a[j]);
    float ej = __expf(a[j] - mj);
    float sj = bsum8(ej);
    a[j] -= mj + __logf(sj);
  }
}

// log_A row k=q, fast form for the serial scans: packed FMA matvec, no
// max-subtraction (logits are structurally O(+-5): weights 0.1-scaled,
// |h|<=1 => |X|<~2.5; normalized log-probs are <=0 so exp never overflows;
// 1e-33 guard keeps log() finite even under hypothetical underflow).
__device__ __forceinline__ void la_row_fast(const f32x2 (&wz2)[32], const float (&wxu)[8],
                                            const float (&bxr)[8],
                                            f32x2 xv0, f32x2 xv1, f32x2 xv2, f32x2 xv3,
                                            float u, float itemp, float (&a)[8]){
  #pragma unroll
  for (int j = 0; j < 8; ++j){
    f32x2 ac = {bxr[j] + wxu[j] * u, 0.f};
    ac = PKFMA(wz2[j * 4 + 0], xv0, ac);
    ac = PKFMA(wz2[j * 4 + 1], xv1, ac);
    ac = PKFMA(wz2[j * 4 + 2], xv2, ac);
    ac = PKFMA(wz2[j * 4 + 3], xv3, ac);
    a[j] = (ac.x + ac.y) * itemp;
  }
  #pragma unroll
  for (int j = 0; j < 8; ++j){
    float ej = __expf(a[j]);
    float sj = bsum8(ej);
    a[j] -= __logf(sj + 1e-33f);
  }
}

// ---------------- forward & backward HMM scans ----------------
// grid 32 = (b,dir); block 256 = (n, q=k); sequential over T, la recomputed.
// X/U/logB for step t+1 are register-prefetched during step t's math so the
// L2/L3 latency never sits on the serial critical path. All LSEs run without
// max-subtraction (see la_row_fast note); every summed term is a normalized
// log-prob (<=0) plus log_B (<=0), so exp() cannot overflow.
__global__ __launch_bounds__(256, 1)
void scan_kernel(const float* __restrict__ X, const float* __restrict__ U,
                 const float* __restrict__ logB, const float* __restrict__ Wzx,
                 const float* __restrict__ Wxu, const float* __restrict__ bx,
                 const float* __restrict__ Zinit, const void* tempP,
                 float* __restrict__ fwdp, float* __restrict__ bwdp){
  int id = blockIdx.x;
  int dir = id & 1, b = id >> 1;
  int tid = threadIdx.x;
  int n = tid >> 3, q = tid & 7;
  int lane = tid & 63, gb = lane & 56;
  float itemp = 1.f / decode_scalar(tempP);
  f32x2 wz2[32];
  int wb0 = (n * K_ + q) * 64;
  const f32x2* wzr = (const f32x2*)(Wzx + wb0);
  #pragma unroll
  for (int c = 0; c < 32; ++c) wz2[c] = wzr[c];
  float wxu[8], bxr[8];
  #pragma unroll
  for (int j = 0; j < 8; ++j){
    wxu[j] = Wxu[(n * K_ + q) * 8 + j];
    bxr[j] = bx [(n * K_ + q) * 8 + j];
  }

  if (dir == 0){
    // t = 0 : f0 = norm(Z_init + log_B[:,0])
    float lb = logB[(size_t)(b * T_) * 256 + tid];
    float v  = Zinit[tid] + lb;
    float m  = bmax8(v); float e = __expf(v - m); float ss = bsum8(e);
    float p  = v - m - __logf(ss);
    fwdp[(size_t)(b * T_) * 256 + tid] = p;
    float prev[8];
    #pragma unroll
    for (int j = 0; j < 8; ++j) prev[j] = __shfl(p, gb + j);
    // prefetch for t = 1 : X(t=0), U(t=1), logB(t=1)
    float pxp[8], pu, plb;
    {
      const float* xr = X + (size_t)(b * T_) * 256 + n * 8;
      #pragma unroll
      for (int h = 0; h < 8; ++h) pxp[h] = xr[h];
      pu  = U[(b * T_ + 1) * N_ + n];
      plb = logB[(size_t)(b * T_ + 1) * 256 + tid];
    }
    for (int t = 1; t < T_; ++t){
      f32x2 xv0 = {pxp[0], pxp[1]}, xv1 = {pxp[2], pxp[3]};
      f32x2 xv2 = {pxp[4], pxp[5]}, xv3 = {pxp[6], pxp[7]};
      float u = pu, lbq = plb;
      if (t + 1 < T_){
        const float* xr = X + (size_t)(b * T_ + t) * 256 + n * 8;
        #pragma unroll
        for (int h = 0; h < 8; ++h) pxp[h] = xr[h];
        pu  = U[(b * T_ + t + 1) * N_ + n];
        plb = logB[(size_t)(b * T_ + t + 1) * 256 + tid];
      }
      float a[8];
      la_row_fast(wz2, wxu, bxr, xv0, xv1, xv2, xv3, u, itemp, a);
      float se = 0.f;
      #pragma unroll
      for (int j = 0; j < 8; ++j) se += __expf(a[j] + prev[j]);
      float val = lbq + __logf(se + 1e-33f);
      float e2 = __expf(val); float s2 = bsum8(e2);
      float p2 = val - __logf(s2 + 1e-33f);
      fwdp[(size_t)(b * T_ + t) * 256 + tid] = p2;
      #pragma unroll
      for (int j = 0; j < 8; ++j) prev[j] = __shfl(p2, gb + j);
    }
  } else {
    float nxt[8];
    #pragma unroll
    for (int j = 0; j < 8; ++j) nxt[j] = 0.f;
    bwdp[(size_t)(b * T_ + T_ - 1) * 256 + tid] = 0.f;
    // first processed t = T-2 uses bt1 = T-1: X(T-2), U(T-1), logB(T-1)
    float pxp[8], pu, plb;
    {
      const float* xr = X + (size_t)(b * T_ + T_ - 2) * 256 + n * 8;
      #pragma unroll
      for (int h = 0; h < 8; ++h) pxp[h] = xr[h];
      pu  = U[(b * T_ + T_ - 1) * N_ + n];
      plb = logB[(size_t)(b * T_ + T_ - 1) * 256 + tid];
    }
    for (int t = T_ - 2; t >= 0; --t){
      f32x2 xv0 = {pxp[0], pxp[1]}, xv1 = {pxp[2], pxp[3]};
      f32x2 xv2 = {pxp[4], pxp[5]}, xv3 = {pxp[6], pxp[7]};
      float u = pu, lbq = plb;
      if (t > 0){
        // next iteration (t-1) uses bt1 = t: X(t-1), U(t), logB(t)
        const float* xr = X + (size_t)(b * T_ + t - 1) * 256 + n * 8;
        #pragma unroll
        for (int h = 0; h < 8; ++h) pxp[h] = xr[h];
        pu  = U[(b * T_ + t) * N_ + n];
        plb = logB[(size_t)(b * T_ + t) * 256 + tid];
      }
      float a[8];
      la_row_fast(wz2, wxu, bxr, xv0, xv1, xv2, xv3, u, itemp, a);
      float nq = nxt[0];
      #pragma unroll
      for (int j = 1; j < 8; ++j) nq = (q == j) ? nxt[j] : nq;
      float out[8];
      #pragma unroll
      for (int j = 0; j < 8; ++j){
        float ej = __expf(nq + a[j] + lbq);   // contribution of k=q to out[j]
        float sj = bsum8(ej);
        out[j] = __logf(sj + 1e-33f);         // LSE over k, replicated on all lanes
      }
      float se = 0.f;
      #pragma unroll
      for (int j = 0; j < 8; ++j) se += __expf(out[j]);
      float lse = __logf(se + 1e-33f);
      #pragma unroll
      for (int j = 0; j < 8; ++j) nxt[j] = out[j] - lse;
      float own = nxt[0];
      #pragma unroll
      for (int j = 1; j < 8; ++j) own = (q == j) ? nxt[j] : own;
      bwdp[(size_t)(b * T_ + t) * 256 + tid] = own;
    }
  }
}

// ---------------- final reductions: Y_prob, init_prob, seq_prob, gamma ----------------
// grid (40,16), block 256 = (n,q); 25 t per block; double accumulators via atomics.
__global__ __launch_bounds__(256, 2)
void final_kernel(const float* __restrict__ X, const float* __restrict__ U,
                  const float* __restrict__ logB, const float* __restrict__ fwdp,
                  const float* __restrict__ bwdp, const float* __restrict__ Wzx,
                  const float* __restrict__ Wxu, const float* __restrict__ bx,
                  const float* __restrict__ Zinit, const float* __restrict__ Wyx,
                  const float* __restrict__ Wyxb, const float* __restrict__ Y,
                  const void* tempP, double* __restrict__ acc){
  int b  = blockIdx.y;
  int t0 = blockIdx.x * 25;
  int tid = threadIdx.x;
  int n = tid >> 3, q = tid & 7;
  int lane = tid & 63, wid = tid >> 6;
  float itemp = 1.f / decode_scalar(tempP);
  float wz[64];
  int wb0 = (n * K_ + q) * 64;
  #pragma unroll
  for (int c = 0; c < 64; ++c) wz[c] = Wzx[wb0 + c];
  float wxu[8], bxr[8];
  #pragma unroll
  for (int j = 0; j < 8; ++j){
    wxu[j] = Wxu[(n * K_ + q) * 8 + j];
    bxr[j] = bx [(n * K_ + q) * 8 + j];
  }
  float wy = Wyx[tid];
  __shared__ float lys[4];
  __shared__ float red[4][4];
  float aY = 0.f, aI = 0.f, aS = 0.f, aG = 0.f;
  for (int t = t0; t < t0 + 25; ++t){
    size_t bt  = (size_t)b * T_ + t;
    size_t idx = bt * 256 + tid;
    float f  = fwdp[idx];
    float bw = bwdp[idx];
    float s  = f + bw;
    float m  = bmax8(s); float e = __expf(s - m); float ss = bsum8(e);
    float g1 = s - m - __logf(ss);
    aG += g1;
    if (t == 0){
      aI += __expf(g1) * (logB[idx] + Zinit[tid]);
    } else {
      float xp[8];
      const float* xr = X + (bt - 1) * 256 + n * 8;
      #pragma unroll
      for (int h = 0; h < 8; ++h) xp[h] = xr[h];
      float uu = U[bt * N_ + n];
      float a[8];
      la_row_reg(wz, wxu, bxr, xp, uu, itemp, a);
      float lbq = logB[idx];
      float fp[8];
      const float* frow = fwdp + (bt - 1) * 256 + n * 8;
      #pragma unroll
      for (int j = 0; j < 8; ++j) fp[j] = frow[j];
      float rr[8];
      float mx = -3.4e38f;
      #pragma unroll
      for (int j = 0; j < 8; ++j){ rr[j] = fp[j] + bw + a[j] + lbq; mx = fmaxf(mx, rr[j]); }
      mx = bmax8(mx);                      // joint (k,j) max
      float se = 0.f;
      #pragma unroll
      for (int j = 0; j < 8; ++j) se += __expf(rr[j] - mx);
      se = bsum8(se);                      // joint (k,j) sum
      float lse = mx + __logf(se);
      const float* lbrow = logB + bt * 256 + n * 8;
      float part = 0.f;
      #pragma unroll
      for (int j = 0; j < 8; ++j) part += __expf(rr[j] - lse) * (a[j] + lbrow[j]);
      aS += part;
    }
    // Y_est for this (b,t): block-wide dot(X_row, W_yx_w)
    float yv = X[bt * 256 + tid] * wy;
    #pragma unroll
    for (int msk = 1; msk < 64; msk <<= 1) yv += __shfl_xor(yv, msk);
    if (lane == 0) lys[wid] = yv;
    __syncthreads();
    if (tid == 0){
      float ye = lys[0] + lys[1] + lys[2] + lys[3] + Wyxb[0] - Y[bt];
      aY -= ye * ye;
    }
    __syncthreads();
  }
  // block reduce the four partials, one set of double atomics per block
  #pragma unroll
  for (int r = 0; r < 4; ++r){
    float v = (r == 0) ? aY : (r == 1) ? aI : (r == 2) ? aS : aG;
    #pragma unroll
    for (int msk = 1; msk < 64; msk <<= 1) v += __shfl_xor(v, msk);
    if (lane == 0) red[r][wid] = v;
  }
  __syncthreads();
  if (tid < 4){
    double v = (double)red[tid][0] + (double)red[tid][1]
             + (double)red[tid][2] + (double)red[tid][3];
    atomicAdd(&acc[tid], v);
  }
}

__global__ void out_kernel(const double* __restrict__ acc, float* __restrict__ out){
  int i = threadIdx.x;
  if (i == 0) out[0] = (float)acc[0];                    // Y_prob
  if (i == 1) out[1] = (float)acc[1];                    // init_prob
  if (i == 2) out[2] = (float)acc[2];                    // seq_prob
  if (i == 3) out[3] = (float)(acc[3] / (double)K_);     // gamma_prior_prob
}

extern "C" void kernel_launch(void* const* d_in, const int* in_sizes, int n_in,
                              void* d_out, int out_size, void* d_ws, size_t ws_size,
                              hipStream_t stream){
  const float* Y       = (const float*)d_in[0];
  const float* U_raw   = (const float*)d_in[1];
  const float* C_syn   = (const float*)d_in[2];
  const float* U_scale = (const float*)d_in[3];
  const float* Z_init  = (const float*)d_in[4];
  const float* W_zx    = (const float*)d_in[5];
  const float* W_xx    = (const float*)d_in[6];
  const float* W_xu    = (const float*)d_in[7];
  const float* b_x     = (const float*)d_in[8];
  const float* W_yx_w  = (const float*)d_in[9];
  const float* W_yx_b  = (const float*)d_in[10];
  const float* Wih_f   = (const float*)d_in[11];
  const float* Whh_f   = (const float*)d_in[12];
  const float* bih_f   = (const float*)d_in[13];
  const float* bhh_f   = (const float*)d_in[14];
  const float* Wih_b   = (const float*)d_in[15];
  const float* Whh_b   = (const float*)d_in[16];
  const float* bih_b   = (const float*)d_in[17];
  const float* bhh_b   = (const float*)d_in[18];
  const float* enc_W   = (const float*)d_in[19];
  const float* enc_b   = (const float*)d_in[20];
  const void*  tempP   = d_in[21];

  char* ws = (char*)d_ws;
  size_t off = 0;
  auto alloc = [&](size_t elems) -> float* {
    float* p = (float*)(ws + off);
    off += elems * sizeof(float);
    off = (off + 255) & ~(size_t)255;
    return p;
  };
  float* U    = alloc((size_t)B_ * T_ * N_);        //  2.05 MB
  float* giF  = alloc((size_t)T_ * B_ * G3_);       // 24.58 MB
  float* giB  = alloc((size_t)T_ * B_ * G3_);       // 24.58 MB
  float* ht   = alloc((size_t)T_ * B_ * 256);       // 16.38 MB
  float* X    = alloc((size_t)B_ * T_ * 256);       // 16.38 MB
  float* logB = alloc((size_t)B_ * T_ * 256);       // 16.38 MB
  float* fwdp = alloc((size_t)B_ * T_ * 256);       // 16.38 MB
  float* bwdp = alloc((size_t)B_ * T_ * 256);       // 16.38 MB
  double* acc = (double*)(ws + off);                // 32 B    (total ~133.2 MB)

  hipMemsetAsync(acc, 0, 4 * sizeof(double), stream);
  u_kernel   <<<B_ * T_ / 8, 256, 0, stream>>>(U_raw, U_scale, C_syn, U);
  gi_kernel  <<<B_ * T_ / 64, G3_, 0, stream>>>(Y, U, Wih_f, bih_f, Wih_b, bih_b, giF, giB);
  gru_kernel <<<32, G3_, 0, stream>>>(Whh_f, bhh_f, Whh_b, bhh_b, giF, giB, ht);
  x_kernel   <<<B_ * T_ / 8, 256, 0, stream>>>(ht, enc_W, enc_b, X);
  logB_kernel<<<dim3(40, 16), 256, 0, stream>>>(X, U, W_xx, W_xu, b_x, logB);
  scan_kernel<<<32, 256, 0, stream>>>(X, U, logB, W_zx, W_xu, b_x, Z_init, tempP, fwdp, bwdp);
  final_kernel<<<dim3(40, 16), 256, 0, stream>>>(X, U, logB, fwdp, bwdp, W_zx, W_xu, b_x,
                                                 Z_init, W_yx_w, W_yx_b, Y, tempP, acc);
  out_kernel <<<1, 64, 0, stream>>>(acc, (float*)d_out);
}

// Round 6
// 2806.694 us; speedup vs baseline: 1.0987x; 1.0987x over previous
//
#include <hip/hip_runtime.h>

// RSLDS forward pipeline for MI355X (gfx950).
// B=16 T=1000 N=32 K=H=8 R=128 IN=256. Output: 4 f32 scalars
// (Y_prob, init_prob, seq_prob, gamma_prior_prob).
//
// R3: 3-phase chunked parallel scan (LSE semiring) replacing the serial scan.
// R4: gru_kernel restructured 384thr/2barrier -> 128thr/3rows/1barrier with
//     double-buffered h in LDS; gate inputs are thread-local (no gh LDS trip).
// R5: unchanged (held stable for validation; full index-algebra re-audit).

constexpr int B_  = 16;
constexpr int T_  = 1000;
constexpr int N_  = 32;
constexpr int K_  = 8;
constexpr int R_  = 128;
constexpr int IN_ = 256;
constexpr int G3_ = 3 * R_;   // 384
constexpr int L_  = 25;       // chunk length (steps)
constexpr int C_  = 40;       // chunks; covers tau = 1..999

typedef float f32x2 __attribute__((ext_vector_type(2)));
#define PKFMA(w, x, acc) __builtin_elementwise_fma((w), (x), (acc))

// ---------------- helpers ----------------
__device__ __forceinline__ float bmax8(float x){
  x = fmaxf(x, __shfl_xor(x, 1));
  x = fmaxf(x, __shfl_xor(x, 2));
  x = fmaxf(x, __shfl_xor(x, 4));
  return x;
}
__device__ __forceinline__ float bsum8(float x){
  x += __shfl_xor(x, 1);
  x += __shfl_xor(x, 2);
  x += __shfl_xor(x, 4);
  return x;
}
__device__ __forceinline__ float decode_scalar(const void* p){
  int iv = *(const int*)p;
  if (iv > -1000000 && iv < 1000000) return (float)iv;
  return *(const float*)p;
}

// ---------------- U = (U_raw * U_scale) @ C_syn^T : (B,T,N) ----------------
__global__ void u_kernel(const float* __restrict__ U_raw, const float* __restrict__ U_scale,
                         const float* __restrict__ C_syn, float* __restrict__ U){
  __shared__ float us[8][IN_];
  int tid = threadIdx.x;
  int bt0 = blockIdx.x * 8;
  #pragma unroll
  for (int p = 0; p < 8; ++p)
    us[p][tid] = U_raw[(size_t)(bt0 + p) * IN_ + tid] * U_scale[tid];
  __syncthreads();
  int n = tid >> 3, lane = tid & 7;
  float acc[8] = {0.f,0.f,0.f,0.f,0.f,0.f,0.f,0.f};
  for (int c = lane; c < IN_; c += 8){
    float cs = C_syn[n * IN_ + c];
    #pragma unroll
    for (int p = 0; p < 8; ++p) acc[p] += cs * us[p][c];
  }
  #pragma unroll
  for (int p = 0; p < 8; ++p){
    float v = bsum8(acc[p]);
    if (lane == 0) U[(bt0 + p) * N_ + n] = v;
  }
}

// ---------------- gi = enc_in @ Wih^T + bih : (T,B,384) x2 dirs ----------------
__global__ void gi_kernel(const float* __restrict__ Y, const float* __restrict__ U,
                          const float* __restrict__ WihF, const float* __restrict__ bihF,
                          const float* __restrict__ WihB, const float* __restrict__ bihB,
                          float* __restrict__ giF, float* __restrict__ giB){
  int i = threadIdx.x;
  float wf[N_ + 1], wb[N_ + 1];
  #pragma unroll
  for (int c = 0; c < N_ + 1; ++c){
    wf[c] = WihF[i * (N_ + 1) + c];
    wb[c] = WihB[i * (N_ + 1) + c];
  }
  float bf = bihF[i], bb = bihB[i];
  __shared__ float e[N_ + 1];
  for (int it = 0; it < 64; ++it){
    int bt = blockIdx.x * 64 + it;
    int b = bt / T_, t = bt % T_;
    __syncthreads();
    if (i < N_) e[1 + i] = U[bt * N_ + i];
    if (i == N_) e[0] = Y[bt];
    __syncthreads();
    float af = bf, ab = bb;
    #pragma unroll
    for (int c = 0; c < N_ + 1; ++c){ float ev = e[c]; af += ev * wf[c]; ab += ev * wb[c]; }
    int o = (t * B_ + b) * G3_ + i;
    giF[o] = af; giB[o] = ab;
  }
}

// ---------------- bidirectional GRU, persistent: 32 blocks = (dir,b) ----------------
// 128 threads; thread i owns rows i (r), 128+i (z), 256+i (n) of Whh in 192
// f32x2 VGPRs. All three gate inputs are thread-local -> no gh LDS round-trip.
// h double-buffered in LDS (WAR-free) -> ONE barrier per step. Own h kept in
// a register. gi for step t+1 register-prefetched during step t's gate phase.
__global__ __launch_bounds__(R_, 1)
void gru_kernel(const float* __restrict__ WhhF, const float* __restrict__ bhhF,
                const float* __restrict__ WhhB, const float* __restrict__ bhhB,
                const float* __restrict__ giF, const float* __restrict__ giB,
                float* __restrict__ ht){
  int id = blockIdx.x;
  int dir = id >> 4, b = id & 15;
  const float* Whh = dir ? WhhB : WhhF;
  const float* bhh = dir ? bhhB : bhhF;
  const float* gi  = dir ? giB  : giF;
  int i = threadIdx.x;   // 0..127
  f32x2 wr2[64], wz2[64], wn2[64];
  {
    const f32x2* a = (const f32x2*)(Whh + (size_t)i * R_);
    const f32x2* c = (const f32x2*)(Whh + (size_t)(R_ + i) * R_);
    const f32x2* d = (const f32x2*)(Whh + (size_t)(2 * R_ + i) * R_);
    #pragma unroll
    for (int k = 0; k < 64; ++k){ wr2[k] = a[k]; wz2[k] = c[k]; wn2[k] = d[k]; }
  }
  float bhr = bhh[i], bhz = bhh[R_ + i], bhn = bhh[2 * R_ + i];
  __shared__ __align__(16) float hsh[2][R_];
  hsh[0][i] = 0.f;
  float hold = 0.f;
  // prefetch gi for the first step
  float pr, pz, pn;
  {
    int base0 = ((dir ? T_ - 1 : 0) * B_ + b) * G3_;
    pr = gi[base0 + i];
    pz = gi[base0 + R_ + i];
    pn = gi[base0 + 2 * R_ + i];
  }
  __syncthreads();
  for (int s = 0; s < T_; ++s){
    int t = dir ? (T_ - 1 - s) : s;
    int cur = s & 1;
    const float4* h4 = (const float4*)hsh[cur];
    f32x2 r0 = {0.f,0.f}, r1 = {0.f,0.f}, r2 = {0.f,0.f}, r3 = {0.f,0.f};
    f32x2 z0 = {0.f,0.f}, z1 = {0.f,0.f}, z2 = {0.f,0.f}, z3 = {0.f,0.f};
    f32x2 n0 = {0.f,0.f}, n1 = {0.f,0.f}, n2 = {0.f,0.f}, n3 = {0.f,0.f};
    #pragma unroll
    for (int c = 0; c < 16; ++c){
      float4 ha = h4[2 * c], hb = h4[2 * c + 1];
      f32x2 p0 = {ha.x, ha.y}, p1 = {ha.z, ha.w};
      f32x2 p2 = {hb.x, hb.y}, p3 = {hb.z, hb.w};
      r0 = PKFMA(wr2[4 * c + 0], p0, r0);
      r1 = PKFMA(wr2[4 * c + 1], p1, r1);
      r2 = PKFMA(wr2[4 * c + 2], p2, r2);
      r3 = PKFMA(wr2[4 * c + 3], p3, r3);
      z0 = PKFMA(wz2[4 * c + 0], p0, z0);
      z1 = PKFMA(wz2[4 * c + 1], p1, z1);
      z2 = PKFMA(wz2[4 * c + 2], p2, z2);
      z3 = PKFMA(wz2[4 * c + 3], p3, z3);
      n0 = PKFMA(wn2[4 * c + 0], p0, n0);
      n1 = PKFMA(wn2[4 * c + 1], p1, n1);
      n2 = PKFMA(wn2[4 * c + 2], p2, n2);
      n3 = PKFMA(wn2[4 * c + 3], p3, n3);
    }
    float hr = bhr + ((r0.x + r0.y) + (r1.x + r1.y)) + ((r2.x + r2.y) + (r3.x + r3.y));
    float hz = bhz + ((z0.x + z0.y) + (z1.x + z1.y)) + ((z2.x + z2.y) + (z3.x + z3.y));
    float hn = bhn + ((n0.x + n0.y) + (n1.x + n1.y)) + ((n2.x + n2.y) + (n3.x + n3.y));
    float gir = pr, giz = pz, gin = pn;
    // issue prefetch for next step (completes during next matvec phase)
    int sn = (s < T_ - 1) ? s + 1 : s;
    int tn = dir ? (T_ - 1 - sn) : sn;
    int basen = (tn * B_ + b) * G3_;
    pr = gi[basen + i];
    pz = gi[basen + R_ + i];
    pn = gi[basen + 2 * R_ + i];
    float r  = 1.f / (1.f + __expf(-(gir + hr)));
    float z  = 1.f / (1.f + __expf(-(giz + hz)));
    float e2 = __expf(2.f * (gin + r * hn));
    float nn = 1.f - 2.f / (e2 + 1.f);   // tanh, saturation-safe
    float hN = (1.f - z) * nn + z * hold;
    hold = hN;
    hsh[cur ^ 1][i] = hN;
    ht[(size_t)(t * B_ + b) * 256 + dir * R_ + i] = hN;
    __syncthreads();
  }
}

// ---------------- X = h @ enc_W^T + enc_b : (B,T,256) ----------------
__global__ void x_kernel(const float* __restrict__ ht, const float* __restrict__ encW,
                         const float* __restrict__ encb, float* __restrict__ X){
  __shared__ __align__(16) float hs[8][256];
  int tid = threadIdx.x;
  int bt0 = blockIdx.x * 8;
  #pragma unroll
  for (int p = 0; p < 8; ++p){
    int bt = bt0 + p;
    int b = bt / T_, t = bt % T_;
    hs[p][tid] = ht[(size_t)(t * B_ + b) * 256 + tid];
  }
  __syncthreads();
  float acc[8] = {0.f,0.f,0.f,0.f,0.f,0.f,0.f,0.f};
  const float4* w4 = (const float4*)(encW + (size_t)tid * 256);
  for (int c4 = 0; c4 < 64; ++c4){
    float4 wv = w4[c4];
    #pragma unroll
    for (int p = 0; p < 8; ++p){
      float4 hv = *(const float4*)&hs[p][c4 * 4];
      acc[p] += wv.x * hv.x + wv.y * hv.y + wv.z * hv.z + wv.w * hv.w;
    }
  }
  float eb = encb[tid];
  #pragma unroll
  for (int p = 0; p < 8; ++p)
    X[(size_t)(bt0 + p) * 256 + tid] = acc[p] + eb;
}

// ---------------- log_B : (B,T,N,K) ----------------
__global__ __launch_bounds__(256, 2)
void logB_kernel(const float* __restrict__ X, const float* __restrict__ U,
                 const float* __restrict__ Wxx, const float* __restrict__ Wxu,
                 const float* __restrict__ bx, float* __restrict__ logB){
  int b  = blockIdx.y;
  int t0 = blockIdx.x * 25;
  int tid = threadIdx.x;
  int n = tid >> 3, k = tid & 7;
  int wb = (n * K_ + k) * 64;
  float wxx[64];
  #pragma unroll
  for (int c = 0; c < 64; ++c) wxx[c] = Wxx[wb + c];
  float wxu[8], bxr[8];
  #pragma unroll
  for (int h = 0; h < 8; ++h){
    wxu[h] = Wxu[(n * K_ + k) * 8 + h];
    bxr[h] = bx [(n * K_ + k) * 8 + h];
  }
  for (int t = t0; t < t0 + 25; ++t){
    int bt = b * T_ + t;
    const float* xrow = X + (size_t)bt * 256 + n * 8;
    float xo[8], xc[8];
    #pragma unroll
    for (int h = 0; h < 8; ++h) xc[h] = xrow[h];
    if (t > 0){
      #pragma unroll
      for (int h = 0; h < 8; ++h) xo[h] = xrow[h - 256];
    } else {
      #pragma unroll
      for (int h = 0; h < 8; ++h) xo[h] = 0.f;
    }
    float u = U[bt * N_ + n];
    float s = 0.f;
    #pragma unroll
    for (int h = 0; h < 8; ++h){
      float xe = xo[h] + wxu[h] * u + bxr[h];
      #pragma unroll
      for (int j = 0; j < 8; ++j) xe += wxx[h * 8 + j] * xo[j];
      float d = xe - xc[h];
      s += d * d;
    }
    logB[(size_t)bt * 256 + tid] = -s;
  }
}

// log_A row k=q (max-subtraction form, used by final_kernel):
__device__ __forceinline__ void la_row_reg(const float (&wz)[64], const float (&wxu)[8],
                                           const float (&bxr)[8], const float (&xp)[8],
                                           float u, float itemp, float (&a)[8]){
  #pragma unroll
  for (int j = 0; j < 8; ++j){
    float x = bxr[j] + wxu[j] * u;
    #pragma unroll
    for (int h = 0; h < 8; ++h) x += wz[j * 8 + h] * xp[h];
    a[j] = x * itemp;
  }
  #pragma unroll
  for (int j = 0; j < 8; ++j){
    float mj = bmax8(a[j]);
    float ej = __expf(a[j] - mj);
    float sj = bsum8(ej);
    a[j] -= mj + __logf(sj);
  }
}

// log_A row k=q, fast no-max form (validated: absmax was 0.0 in R3 bench).
__device__ __forceinline__ void la_row_fast(const f32x2 (&wz2)[32], const float (&wxu)[8],
                                            const float (&bxr)[8],
                                            f32x2 xv0, f32x2 xv1, f32x2 xv2, f32x2 xv3,
                                            float u, float itemp, float (&a)[8]){
  #pragma unroll
  for (int j = 0; j < 8; ++j){
    f32x2 ac = {bxr[j] + wxu[j] * u, 0.f};
    ac = PKFMA(wz2[j * 4 + 0], xv0, ac);
    ac = PKFMA(wz2[j * 4 + 1], xv1, ac);
    ac = PKFMA(wz2[j * 4 + 2], xv2, ac);
    ac = PKFMA(wz2[j * 4 + 3], xv3, ac);
    a[j] = (ac.x + ac.y) * itemp;
  }
  #pragma unroll
  for (int j = 0; j < 8; ++j){
    float ej = __expf(a[j]);
    float sj = bsum8(ej);
    a[j] -= __logf(sj + 1e-33f);
  }
}

// ---------------- phase 1: chunk transition-matrix products ----------------
// One wave per (b,n,chunk). Lane l holds M[r = l&7, c = l>>3] (row=k, col=j).
// Step: Mnew[r,c] = lb[r] + LSE_m( a[r,m] + M[m,c] ), local-max-subtracted,
// then globally recentered (constant shifts cancel in later normalizations).
__global__ __launch_bounds__(256, 2)
void chunkmat_kernel(const float* __restrict__ X, const float* __restrict__ U,
                     const float* __restrict__ logB, const float* __restrict__ Wzx,
                     const float* __restrict__ Wxu, const float* __restrict__ bx,
                     const void* tempP, float* __restrict__ Mbuf){
  int l = threadIdx.x & 63;
  int unit = blockIdx.x * 4 + (threadIdx.x >> 6);  // < B_*N_*C_ = 20480
  int ci = unit % C_;
  int bn = unit / C_;
  int n = bn & (N_ - 1);
  int b = bn >> 5;
  int r = l & 7;
  float itemp = 1.f / decode_scalar(tempP);
  f32x2 wz2[32];
  const f32x2* wzr = (const f32x2*)(Wzx + (n * K_ + r) * 64);
  #pragma unroll
  for (int c = 0; c < 32; ++c) wz2[c] = wzr[c];
  float wxu[8], bxr[8];
  #pragma unroll
  for (int j = 0; j < 8; ++j){
    wxu[j] = Wxu[(n * K_ + r) * 8 + j];
    bxr[j] = bx [(n * K_ + r) * 8 + j];
  }
  int tlo = ci * L_ + 1;
  int thi = min(ci * L_ + L_, T_ - 1);
  float M = (r == (l >> 3)) ? 0.f : -1e30f;
  // prefetch tau = tlo
  float pxp[8], pu, plb;
  {
    const float* xr = X + (size_t)(b * T_ + tlo - 1) * 256 + n * 8;
    #pragma unroll
    for (int h = 0; h < 8; ++h) pxp[h] = xr[h];
    pu  = U[(b * T_ + tlo) * N_ + n];
    plb = logB[(size_t)(b * T_ + tlo) * 256 + n * 8 + r];
  }
  for (int tau = tlo; tau <= thi; ++tau){
    f32x2 xv0 = {pxp[0], pxp[1]}, xv1 = {pxp[2], pxp[3]};
    f32x2 xv2 = {pxp[4], pxp[5]}, xv3 = {pxp[6], pxp[7]};
    float u = pu, lbr = plb;
    if (tau + 1 <= thi){
      const float* xr = X + (size_t)(b * T_ + tau) * 256 + n * 8;
      #pragma unroll
      for (int h = 0; h < 8; ++h) pxp[h] = xr[h];
      pu  = U[(b * T_ + tau + 1) * N_ + n];
      plb = logB[(size_t)(b * T_ + tau + 1) * 256 + n * 8 + r];
    }
    float a[8];
    la_row_fast(wz2, wxu, bxr, xv0, xv1, xv2, xv3, u, itemp, a);
    float tm[8];
    float mx = -3.4e38f;
    #pragma unroll
    for (int m = 0; m < 8; ++m){
      float Mg = __shfl(M, (l & 56) | m);
      tm[m] = a[m] + Mg;
      mx = fmaxf(mx, tm[m]);
    }
    float se = 0.f;
    #pragma unroll
    for (int m = 0; m < 8; ++m) se += __expf(tm[m] - mx);
    float Mn = lbr + mx + __logf(se);
    // global recenter (constant over the matrix -> cancels downstream)
    float gm = Mn;
    #pragma unroll
    for (int msk = 1; msk < 64; msk <<= 1) gm = fmaxf(gm, __shfl_xor(gm, msk));
    M = Mn - gm;
  }
  Mbuf[((size_t)(ci * B_ + b) * N_ + n) * 64 + l] = M;
}

// ---------------- phase 2: serial chunk-boundary scan (tiny) ----------------
// grid 32 = (b,dir); block 256 = (n,q). fwd: f_{ci+1} = norm(M_ci . f_ci);
// bwd: g_{ci-1} = norm(M_ci^T . g_ci). Also writes fwdp[t=0] and bwdp[t=999].
__global__ __launch_bounds__(256, 1)
void boundary_kernel(const float* __restrict__ logB, const float* __restrict__ Zinit,
                     const float* __restrict__ Mbuf, float* __restrict__ fB,
                     float* __restrict__ gB, float* __restrict__ fwdp,
                     float* __restrict__ bwdp){
  int dir = blockIdx.x & 1, b = blockIdx.x >> 1;
  int tid = threadIdx.x;
  int n = tid >> 3, q = tid & 7;
  int gb = (tid & 63) & 56;
  if (dir == 0){
    float v = Zinit[tid] + logB[(size_t)(b * T_) * 256 + tid];
    float m = bmax8(v); float e = __expf(v - m); float ss = bsum8(e);
    float p = v - m - __logf(ss);
    fwdp[(size_t)(b * T_) * 256 + tid] = p;
    fB[((size_t)(0 * B_ + b) * N_ + n) * 8 + q] = p;
    float prev[8];
    #pragma unroll
    for (int j = 0; j < 8; ++j) prev[j] = __shfl(p, gb + j);
    for (int ci = 0; ci < C_ - 1; ++ci){
      const float* mrow = Mbuf + ((size_t)(ci * B_ + b) * N_ + n) * 64;
      float tm[8]; float mx = -3.4e38f;
      #pragma unroll
      for (int c = 0; c < 8; ++c){ tm[c] = mrow[(c << 3) + q] + prev[c]; mx = fmaxf(mx, tm[c]); }
      float se = 0.f;
      #pragma unroll
      for (int c = 0; c < 8; ++c) se += __expf(tm[c] - mx);
      float val = mx + __logf(se);
      float m2 = bmax8(val); float e2 = __expf(val - m2); float s2 = bsum8(e2);
      float p2 = val - m2 - __logf(s2);
      fB[((size_t)((ci + 1) * B_ + b) * N_ + n) * 8 + q] = p2;
      #pragma unroll
      for (int j = 0; j < 8; ++j) prev[j] = __shfl(p2, gb + j);
    }
  } else {
    bwdp[(size_t)(b * T_ + T_ - 1) * 256 + tid] = 0.f;
    gB[((size_t)((C_ - 1) * B_ + b) * N_ + n) * 8 + q] = 0.f;
    float g[8];
    #pragma unroll
    for (int j = 0; j < 8; ++j) g[j] = 0.f;
    for (int ci = C_ - 1; ci >= 1; --ci){
      const float* mcol = Mbuf + ((size_t)(ci * B_ + b) * N_ + n) * 64 + (q << 3);
      float tm[8]; float mx = -3.4e38f;
      #pragma unroll
      for (int k = 0; k < 8; ++k){ tm[k] = mcol[k] + g[k]; mx = fmaxf(mx, tm[k]); }
      float se = 0.f;
      #pragma unroll
      for (int k = 0; k < 8; ++k) se += __expf(tm[k] - mx);
      float val = mx + __logf(se);
      float m2 = bmax8(val); float e2 = __expf(val - m2); float s2 = bsum8(e2);
      float p2 = val - m2 - __logf(s2);
      gB[((size_t)((ci - 1) * B_ + b) * N_ + n) * 8 + q] = p2;
      #pragma unroll
      for (int k = 0; k < 8; ++k) g[k] = __shfl(p2, gb + k);
    }
  }
}

// ---------------- phase 3: within-chunk recursions (parallel over chunks) ----
// grid 1280 = (dir, ci, b); block 256 = (n,q). Body identical to the old
// (validated) serial scan, but only L_ steps from the chunk-boundary vector.
__global__ __launch_bounds__(256, 2)
void chunkscan_kernel(const float* __restrict__ X, const float* __restrict__ U,
                      const float* __restrict__ logB, const float* __restrict__ Wzx,
                      const float* __restrict__ Wxu, const float* __restrict__ bx,
                      const float* __restrict__ fB, const float* __restrict__ gB,
                      const void* tempP, float* __restrict__ fwdp,
                      float* __restrict__ bwdp){
  int bid = blockIdx.x;
  int dir = bid & 1;
  int rest = bid >> 1;
  int ci = rest % C_;
  int b = rest / C_;
  int tid = threadIdx.x;
  int n = tid >> 3, q = tid & 7;
  int gb = (tid & 63) & 56;
  float itemp = 1.f / decode_scalar(tempP);
  f32x2 wz2[32];
  const f32x2* wzr = (const f32x2*)(Wzx + (n * K_ + q) * 64);
  #pragma unroll
  for (int c = 0; c < 32; ++c) wz2[c] = wzr[c];
  float wxu[8], bxr[8];
  #pragma unroll
  for (int j = 0; j < 8; ++j){
    wxu[j] = Wxu[(n * K_ + q) * 8 + j];
    bxr[j] = bx [(n * K_ + q) * 8 + j];
  }
  int tlo = ci * L_ + 1;
  int thi = min(ci * L_ + L_, T_ - 1);

  if (dir == 0){
    float p = fB[((size_t)(ci * B_ + b) * N_ + n) * 8 + q];
    float prev[8];
    #pragma unroll
    for (int j = 0; j < 8; ++j) prev[j] = __shfl(p, gb + j);
    float pxp[8], pu, plb;
    {
      const float* xr = X + (size_t)(b * T_ + tlo - 1) * 256 + n * 8;
      #pragma unroll
      for (int h = 0; h < 8; ++h) pxp[h] = xr[h];
      pu  = U[(b * T_ + tlo) * N_ + n];
      plb = logB[(size_t)(b * T_ + tlo) * 256 + tid];
    }
    for (int t = tlo; t <= thi; ++t){
      f32x2 xv0 = {pxp[0], pxp[1]}, xv1 = {pxp[2], pxp[3]};
      f32x2 xv2 = {pxp[4], pxp[5]}, xv3 = {pxp[6], pxp[7]};
      float u = pu, lbq = plb;
      if (t + 1 <= thi){
        const float* xr = X + (size_t)(b * T_ + t) * 256 + n * 8;
        #pragma unroll
        for (int h = 0; h < 8; ++h) pxp[h] = xr[h];
        pu  = U[(b * T_ + t + 1) * N_ + n];
        plb = logB[(size_t)(b * T_ + t + 1) * 256 + tid];
      }
      float a[8];
      la_row_fast(wz2, wxu, bxr, xv0, xv1, xv2, xv3, u, itemp, a);
      float se = 0.f;
      #pragma unroll
      for (int j = 0; j < 8; ++j) se += __expf(a[j] + prev[j]);
      float val = lbq + __logf(se + 1e-33f);
      float e2 = __expf(val); float s2 = bsum8(e2);
      float p2 = val - __logf(s2 + 1e-33f);
      fwdp[(size_t)(b * T_ + t) * 256 + tid] = p2;
      #pragma unroll
      for (int j = 0; j < 8; ++j) prev[j] = __shfl(p2, gb + j);
    }
  } else {
    float p = gB[((size_t)(ci * B_ + b) * N_ + n) * 8 + q];
    float nxt[8];
    #pragma unroll
    for (int j = 0; j < 8; ++j) nxt[j] = __shfl(p, gb + j);
    float pxp[8], pu, plb;
    {
      const float* xr = X + (size_t)(b * T_ + thi - 1) * 256 + n * 8;
      #pragma unroll
      for (int h = 0; h < 8; ++h) pxp[h] = xr[h];
      pu  = U[(b * T_ + thi) * N_ + n];
      plb = logB[(size_t)(b * T_ + thi) * 256 + tid];
    }
    for (int tau = thi; tau >= tlo; --tau){
      f32x2 xv0 = {pxp[0], pxp[1]}, xv1 = {pxp[2], pxp[3]};
      f32x2 xv2 = {pxp[4], pxp[5]}, xv3 = {pxp[6], pxp[7]};
      float u = pu, lbq = plb;
      if (tau - 1 >= tlo){
        const float* xr = X + (size_t)(b * T_ + tau - 2) * 256 + n * 8;
        #pragma unroll
        for (int h = 0; h < 8; ++h) pxp[h] = xr[h];
        pu  = U[(b * T_ + tau - 1) * N_ + n];
        plb = logB[(size_t)(b * T_ + tau - 1) * 256 + tid];
      }
      float a[8];
      la_row_fast(wz2, wxu, bxr, xv0, xv1, xv2, xv3, u, itemp, a);
      float nq = nxt[0];
      #pragma unroll
      for (int j = 1; j < 8; ++j) nq = (q == j) ? nxt[j] : nq;
      float out[8];
      #pragma unroll
      for (int j = 0; j < 8; ++j){
        float ej = __expf(nq + a[j] + lbq);
        float sj = bsum8(ej);
        out[j] = __logf(sj + 1e-33f);
      }
      float se = 0.f;
      #pragma unroll
      for (int j = 0; j < 8; ++j) se += __expf(out[j]);
      float lse = __logf(se + 1e-33f);
      #pragma unroll
      for (int j = 0; j < 8; ++j) nxt[j] = out[j] - lse;
      float own = nxt[0];
      #pragma unroll
      for (int j = 1; j < 8; ++j) own = (q == j) ? nxt[j] : own;
      bwdp[(size_t)(b * T_ + tau - 1) * 256 + tid] = own;
    }
  }
}

// ---------------- final reductions ----------------
__global__ __launch_bounds__(256, 2)
void final_kernel(const float* __restrict__ X, const float* __restrict__ U,
                  const float* __restrict__ logB, const float* __restrict__ fwdp,
                  const float* __restrict__ bwdp, const float* __restrict__ Wzx,
                  const float* __restrict__ Wxu, const float* __restrict__ bx,
                  const float* __restrict__ Zinit, const float* __restrict__ Wyx,
                  const float* __restrict__ Wyxb, const float* __restrict__ Y,
                  const void* tempP, double* __restrict__ acc){
  int b  = blockIdx.y;
  int t0 = blockIdx.x * 25;
  int tid = threadIdx.x;
  int n = tid >> 3, q = tid & 7;
  int lane = tid & 63, wid = tid >> 6;
  float itemp = 1.f / decode_scalar(tempP);
  float wz[64];
  int wb0 = (n * K_ + q) * 64;
  #pragma unroll
  for (int c = 0; c < 64; ++c) wz[c] = Wzx[wb0 + c];
  float wxu[8], bxr[8];
  #pragma unroll
  for (int j = 0; j < 8; ++j){
    wxu[j] = Wxu[(n * K_ + q) * 8 + j];
    bxr[j] = bx [(n * K_ + q) * 8 + j];
  }
  float wy = Wyx[tid];
  __shared__ float lys[4];
  __shared__ float red[4][4];
  float aY = 0.f, aI = 0.f, aS = 0.f, aG = 0.f;
  for (int t = t0; t < t0 + 25; ++t){
    size_t bt  = (size_t)b * T_ + t;
    size_t idx = bt * 256 + tid;
    float f  = fwdp[idx];
    float bw = bwdp[idx];
    float s  = f + bw;
    float m  = bmax8(s); float e = __expf(s - m); float ss = bsum8(e);
    float g1 = s - m - __logf(ss);
    aG += g1;
    if (t == 0){
      aI += __expf(g1) * (logB[idx] + Zinit[tid]);
    } else {
      float xp[8];
      const float* xr = X + (bt - 1) * 256 + n * 8;
      #pragma unroll
      for (int h = 0; h < 8; ++h) xp[h] = xr[h];
      float uu = U[bt * N_ + n];
      float a[8];
      la_row_reg(wz, wxu, bxr, xp, uu, itemp, a);
      float lbq = logB[idx];
      float fp[8];
      const float* frow = fwdp + (bt - 1) * 256 + n * 8;
      #pragma unroll
      for (int j = 0; j < 8; ++j) fp[j] = frow[j];
      float rr[8];
      float mx = -3.4e38f;
      #pragma unroll
      for (int j = 0; j < 8; ++j){ rr[j] = fp[j] + bw + a[j] + lbq; mx = fmaxf(mx, rr[j]); }
      mx = bmax8(mx);
      float se = 0.f;
      #pragma unroll
      for (int j = 0; j < 8; ++j) se += __expf(rr[j] - mx);
      se = bsum8(se);
      float lse = mx + __logf(se);
      const float* lbrow = logB + bt * 256 + n * 8;
      float part = 0.f;
      #pragma unroll
      for (int j = 0; j < 8; ++j) part += __expf(rr[j] - lse) * (a[j] + lbrow[j]);
      aS += part;
    }
    float yv = X[bt * 256 + tid] * wy;
    #pragma unroll
    for (int msk = 1; msk < 64; msk <<= 1) yv += __shfl_xor(yv, msk);
    if (lane == 0) lys[wid] = yv;
    __syncthreads();
    if (tid == 0){
      float ye = lys[0] + lys[1] + lys[2] + lys[3] + Wyxb[0] - Y[bt];
      aY -= ye * ye;
    }
    __syncthreads();
  }
  #pragma unroll
  for (int r = 0; r < 4; ++r){
    float v = (r == 0) ? aY : (r == 1) ? aI : (r == 2) ? aS : aG;
    #pragma unroll
    for (int msk = 1; msk < 64; msk <<= 1) v += __shfl_xor(v, msk);
    if (lane == 0) red[r][wid] = v;
  }
  __syncthreads();
  if (tid < 4){
    double v = (double)red[tid][0] + (double)red[tid][1]
             + (double)red[tid][2] + (double)red[tid][3];
    atomicAdd(&acc[tid], v);
  }
}

__global__ void out_kernel(const double* __restrict__ acc, float* __restrict__ out){
  int i = threadIdx.x;
  if (i == 0) out[0] = (float)acc[0];
  if (i == 1) out[1] = (float)acc[1];
  if (i == 2) out[2] = (float)acc[2];
  if (i == 3) out[3] = (float)(acc[3] / (double)K_);
}

extern "C" void kernel_launch(void* const* d_in, const int* in_sizes, int n_in,
                              void* d_out, int out_size, void* d_ws, size_t ws_size,
                              hipStream_t stream){
  const float* Y       = (const float*)d_in[0];
  const float* U_raw   = (const float*)d_in[1];
  const float* C_syn   = (const float*)d_in[2];
  const float* U_scale = (const float*)d_in[3];
  const float* Z_init  = (const float*)d_in[4];
  const float* W_zx    = (const float*)d_in[5];
  const float* W_xx    = (const float*)d_in[6];
  const float* W_xu    = (const float*)d_in[7];
  const float* b_x     = (const float*)d_in[8];
  const float* W_yx_w  = (const float*)d_in[9];
  const float* W_yx_b  = (const float*)d_in[10];
  const float* Wih_f   = (const float*)d_in[11];
  const float* Whh_f   = (const float*)d_in[12];
  const float* bih_f   = (const float*)d_in[13];
  const float* bhh_f   = (const float*)d_in[14];
  const float* Wih_b   = (const float*)d_in[15];
  const float* Whh_b   = (const float*)d_in[16];
  const float* bih_b   = (const float*)d_in[17];
  const float* bhh_b   = (const float*)d_in[18];
  const float* enc_W   = (const float*)d_in[19];
  const float* enc_b   = (const float*)d_in[20];
  const void*  tempP   = d_in[21];

  char* ws = (char*)d_ws;
  size_t off = 0;
  auto alloc = [&](size_t elems) -> float* {
    float* p = (float*)(ws + off);
    off += elems * sizeof(float);
    off = (off + 255) & ~(size_t)255;
    return p;
  };
  float* U    = alloc((size_t)B_ * T_ * N_);        //  2.05 MB
  float* giF  = alloc((size_t)T_ * B_ * G3_);       // 24.58 MB
  float* giB  = alloc((size_t)T_ * B_ * G3_);       // 24.58 MB
  float* ht   = alloc((size_t)T_ * B_ * 256);       // 16.38 MB
  float* X    = alloc((size_t)B_ * T_ * 256);       // 16.38 MB
  float* logB = alloc((size_t)B_ * T_ * 256);       // 16.38 MB
  float* fwdp = alloc((size_t)B_ * T_ * 256);       // 16.38 MB
  float* bwdp = alloc((size_t)B_ * T_ * 256);       // 16.38 MB
  double* acc = (double*)(ws + off);                // 32 B    (total ~133.2 MB)

  // scan scratch aliased into giF/giB (dead after gru_kernel):
  float* Mbuf = giF;                                   // 40*16*32*64 = 5.24 MB
  float* fB   = giF + (size_t)C_ * B_ * N_ * 64;       // 40*16*32*8  = 0.65 MB
  float* gB   = fB + (size_t)C_ * B_ * N_ * 8;         // 0.65 MB (all < 24.58 MB)

  hipMemsetAsync(acc, 0, 4 * sizeof(double), stream);
  u_kernel   <<<B_ * T_ / 8, 256, 0, stream>>>(U_raw, U_scale, C_syn, U);
  gi_kernel  <<<B_ * T_ / 64, G3_, 0, stream>>>(Y, U, Wih_f, bih_f, Wih_b, bih_b, giF, giB);
  gru_kernel <<<32, R_, 0, stream>>>(Whh_f, bhh_f, Whh_b, bhh_b, giF, giB, ht);
  x_kernel   <<<B_ * T_ / 8, 256, 0, stream>>>(ht, enc_W, enc_b, X);
  logB_kernel<<<dim3(40, 16), 256, 0, stream>>>(X, U, W_xx, W_xu, b_x, logB);
  chunkmat_kernel<<<B_ * N_ * C_ / 4, 256, 0, stream>>>(X, U, logB, W_zx, W_xu, b_x,
                                                        tempP, Mbuf);
  boundary_kernel<<<32, 256, 0, stream>>>(logB, Z_init, Mbuf, fB, gB, fwdp, bwdp);
  chunkscan_kernel<<<2 * C_ * B_, 256, 0, stream>>>(X, U, logB, W_zx, W_xu, b_x,
                                                    fB, gB, tempP, fwdp, bwdp);
  final_kernel<<<dim3(40, 16), 256, 0, stream>>>(X, U, logB, fwdp, bwdp, W_zx, W_xu, b_x,
                                                 Z_init, W_yx_w, W_yx_b, Y, tempP, acc);
  out_kernel <<<1, 64, 0, stream>>>(acc, (float*)d_out);
}

// Round 10
// 1665.660 us; speedup vs baseline: 1.8513x; 1.6850x over previous
//
#include <hip/hip_runtime.h>

// RSLDS forward pipeline for MI355X (gfx950).
// B=16 T=1000 N=32 K=H=8 R=128 IN=256. Output: 4 f32 scalars
// (Y_prob, init_prob, seq_prob, gamma_prior_prob).
//
// R3: 3-phase chunked parallel scan (LSE semiring); validated absmax 0.0.
// R6: R4 gru spilled (VGPR=216 vs 384 needed -> scratch reload each step,
//     1907us). R7 gru: K-split-4, 512 thr, 96 weight VGPRs/thread (fits),
//     3x less LDS h-broadcast, pad-5 partial reduction buffer.
// R8/R9: R7 resubmitted unchanged (GPU unavailable; audit-only rounds).

constexpr int B_  = 16;
constexpr int T_  = 1000;
constexpr int N_  = 32;
constexpr int K_  = 8;
constexpr int R_  = 128;
constexpr int IN_ = 256;
constexpr int G3_ = 3 * R_;   // 384
constexpr int L_  = 25;       // chunk length (steps)
constexpr int C_  = 40;       // chunks; covers tau = 1..999

typedef float f32x2 __attribute__((ext_vector_type(2)));
#define PKFMA(w, x, acc) __builtin_elementwise_fma((w), (x), (acc))

// ---------------- helpers ----------------
__device__ __forceinline__ float bmax8(float x){
  x = fmaxf(x, __shfl_xor(x, 1));
  x = fmaxf(x, __shfl_xor(x, 2));
  x = fmaxf(x, __shfl_xor(x, 4));
  return x;
}
__device__ __forceinline__ float bsum8(float x){
  x += __shfl_xor(x, 1);
  x += __shfl_xor(x, 2);
  x += __shfl_xor(x, 4);
  return x;
}
__device__ __forceinline__ float decode_scalar(const void* p){
  int iv = *(const int*)p;
  if (iv > -1000000 && iv < 1000000) return (float)iv;
  return *(const float*)p;
}

// ---------------- U = (U_raw * U_scale) @ C_syn^T : (B,T,N) ----------------
__global__ void u_kernel(const float* __restrict__ U_raw, const float* __restrict__ U_scale,
                         const float* __restrict__ C_syn, float* __restrict__ U){
  __shared__ float us[8][IN_];
  int tid = threadIdx.x;
  int bt0 = blockIdx.x * 8;
  #pragma unroll
  for (int p = 0; p < 8; ++p)
    us[p][tid] = U_raw[(size_t)(bt0 + p) * IN_ + tid] * U_scale[tid];
  __syncthreads();
  int n = tid >> 3, lane = tid & 7;
  float acc[8] = {0.f,0.f,0.f,0.f,0.f,0.f,0.f,0.f};
  for (int c = lane; c < IN_; c += 8){
    float cs = C_syn[n * IN_ + c];
    #pragma unroll
    for (int p = 0; p < 8; ++p) acc[p] += cs * us[p][c];
  }
  #pragma unroll
  for (int p = 0; p < 8; ++p){
    float v = bsum8(acc[p]);
    if (lane == 0) U[(bt0 + p) * N_ + n] = v;
  }
}

// ---------------- gi = enc_in @ Wih^T + bih : (T,B,384) x2 dirs ----------------
__global__ void gi_kernel(const float* __restrict__ Y, const float* __restrict__ U,
                          const float* __restrict__ WihF, const float* __restrict__ bihF,
                          const float* __restrict__ WihB, const float* __restrict__ bihB,
                          float* __restrict__ giF, float* __restrict__ giB){
  int i = threadIdx.x;
  float wf[N_ + 1], wb[N_ + 1];
  #pragma unroll
  for (int c = 0; c < N_ + 1; ++c){
    wf[c] = WihF[i * (N_ + 1) + c];
    wb[c] = WihB[i * (N_ + 1) + c];
  }
  float bf = bihF[i], bb = bihB[i];
  __shared__ float e[N_ + 1];
  for (int it = 0; it < 64; ++it){
    int bt = blockIdx.x * 64 + it;
    int b = bt / T_, t = bt % T_;
    __syncthreads();
    if (i < N_) e[1 + i] = U[bt * N_ + i];
    if (i == N_) e[0] = Y[bt];
    __syncthreads();
    float af = bf, ab = bb;
    #pragma unroll
    for (int c = 0; c < N_ + 1; ++c){ float ev = e[c]; af += ev * wf[c]; ab += ev * wb[c]; }
    int o = (t * B_ + b) * G3_ + i;
    giF[o] = af; giB[o] = ab;
  }
}

// ---------------- bidirectional GRU, persistent: 32 blocks = (dir,b) ----------------
// R7: 512 threads; thread (i=t&127, g=t>>7) owns rows {i,128+i,256+i} over
// K-slice [32g,32g+32): 48 f32x2 = 96 weight VGPRs (in-register, no spill).
// g is wave-uniform -> h-slice reads are uniform ds_read_b128 broadcasts
// (8/wave/step). Partials reduced via pad-5 LDS buffer (2-way bank = free).
// Threads t<128 run the gate phase; gi prefetched one step ahead.
__global__ __launch_bounds__(512, 2)
void gru_kernel(const float* __restrict__ WhhF, const float* __restrict__ bhhF,
                const float* __restrict__ WhhB, const float* __restrict__ bhhB,
                const float* __restrict__ giF, const float* __restrict__ giB,
                float* __restrict__ ht){
  int id = blockIdx.x;
  int dir = id >> 4, b = id & 15;
  const float* Whh = dir ? WhhB : WhhF;
  const float* bhh = dir ? bhhB : bhhF;
  const float* gi  = dir ? giB  : giF;
  int t = threadIdx.x;        // 0..511
  int i = t & 127;            // row / h index
  int g = t >> 7;             // K-split quarter (wave-uniform)
  f32x2 wr2[16], wz2[16], wn2[16];
  {
    const f32x2* a = (const f32x2*)(Whh + (size_t)i * R_ + 32 * g);
    const f32x2* c = (const f32x2*)(Whh + (size_t)(R_ + i) * R_ + 32 * g);
    const f32x2* d = (const f32x2*)(Whh + (size_t)(2 * R_ + i) * R_ + 32 * g);
    #pragma unroll
    for (int k = 0; k < 16; ++k){ wr2[k] = a[k]; wz2[k] = c[k]; wn2[k] = d[k]; }
  }
  __shared__ __align__(16) float hsh[2][R_];
  __shared__ float part[3][R_][5];   // pad 5: write (5i+g)%32 and read (5i+c)%32 are 2-way
  float bhr = 0.f, bhz = 0.f, bhn = 0.f, pr = 0.f, pz = 0.f, pn = 0.f;
  if (t < R_){
    bhr = bhh[i]; bhz = bhh[R_ + i]; bhn = bhh[2 * R_ + i];
    int base0 = ((dir ? T_ - 1 : 0) * B_ + b) * G3_;
    pr = gi[base0 + i];
    pz = gi[base0 + R_ + i];
    pn = gi[base0 + 2 * R_ + i];
    hsh[0][i] = 0.f;
  }
  float hold = 0.f;
  __syncthreads();
  for (int s = 0; s < T_; ++s){
    int cur = s & 1;
    const float4* h4 = (const float4*)&hsh[cur][32 * g];
    f32x2 r0 = {0.f,0.f}, r1 = {0.f,0.f};
    f32x2 z0 = {0.f,0.f}, z1 = {0.f,0.f};
    f32x2 n0 = {0.f,0.f}, n1 = {0.f,0.f};
    #pragma unroll
    for (int c = 0; c < 8; ++c){
      float4 hv = h4[c];
      f32x2 p0 = {hv.x, hv.y}, p1 = {hv.z, hv.w};
      r0 = PKFMA(wr2[2 * c], p0, r0);  r1 = PKFMA(wr2[2 * c + 1], p1, r1);
      z0 = PKFMA(wz2[2 * c], p0, z0);  z1 = PKFMA(wz2[2 * c + 1], p1, z1);
      n0 = PKFMA(wn2[2 * c], p0, n0);  n1 = PKFMA(wn2[2 * c + 1], p1, n1);
    }
    part[0][i][g] = (r0.x + r0.y) + (r1.x + r1.y);
    part[1][i][g] = (z0.x + z0.y) + (z1.x + z1.y);
    part[2][i][g] = (n0.x + n0.y) + (n1.x + n1.y);
    __syncthreads();
    if (t < R_){
      int tt = dir ? (T_ - 1 - s) : s;
      float hr = bhr + ((part[0][i][0] + part[0][i][1]) + (part[0][i][2] + part[0][i][3]));
      float hz = bhz + ((part[1][i][0] + part[1][i][1]) + (part[1][i][2] + part[1][i][3]));
      float hn = bhn + ((part[2][i][0] + part[2][i][1]) + (part[2][i][2] + part[2][i][3]));
      float gir = pr, giz = pz, gin = pn;
      // prefetch next step's gi (completes during next matvec phase)
      int sn = (s < T_ - 1) ? s + 1 : s;
      int tn = dir ? (T_ - 1 - sn) : sn;
      int basen = (tn * B_ + b) * G3_;
      pr = gi[basen + i];
      pz = gi[basen + R_ + i];
      pn = gi[basen + 2 * R_ + i];
      float r  = 1.f / (1.f + __expf(-(gir + hr)));
      float z  = 1.f / (1.f + __expf(-(giz + hz)));
      float e2 = __expf(2.f * (gin + r * hn));
      float nn = 1.f - 2.f / (e2 + 1.f);   // tanh, saturation-safe
      float hN = (1.f - z) * nn + z * hold;
      hold = hN;
      hsh[cur ^ 1][i] = hN;
      ht[(size_t)(tt * B_ + b) * 256 + dir * R_ + i] = hN;
    }
    __syncthreads();
  }
}

// ---------------- X = h @ enc_W^T + enc_b : (B,T,256) ----------------
__global__ void x_kernel(const float* __restrict__ ht, const float* __restrict__ encW,
                         const float* __restrict__ encb, float* __restrict__ X){
  __shared__ __align__(16) float hs[8][256];
  int tid = threadIdx.x;
  int bt0 = blockIdx.x * 8;
  #pragma unroll
  for (int p = 0; p < 8; ++p){
    int bt = bt0 + p;
    int b = bt / T_, t = bt % T_;
    hs[p][tid] = ht[(size_t)(t * B_ + b) * 256 + tid];
  }
  __syncthreads();
  float acc[8] = {0.f,0.f,0.f,0.f,0.f,0.f,0.f,0.f};
  const float4* w4 = (const float4*)(encW + (size_t)tid * 256);
  for (int c4 = 0; c4 < 64; ++c4){
    float4 wv = w4[c4];
    #pragma unroll
    for (int p = 0; p < 8; ++p){
      float4 hv = *(const float4*)&hs[p][c4 * 4];
      acc[p] += wv.x * hv.x + wv.y * hv.y + wv.z * hv.z + wv.w * hv.w;
    }
  }
  float eb = encb[tid];
  #pragma unroll
  for (int p = 0; p < 8; ++p)
    X[(size_t)(bt0 + p) * 256 + tid] = acc[p] + eb;
}

// ---------------- log_B : (B,T,N,K) ----------------
__global__ __launch_bounds__(256, 2)
void logB_kernel(const float* __restrict__ X, const float* __restrict__ U,
                 const float* __restrict__ Wxx, const float* __restrict__ Wxu,
                 const float* __restrict__ bx, float* __restrict__ logB){
  int b  = blockIdx.y;
  int t0 = blockIdx.x * 25;
  int tid = threadIdx.x;
  int n = tid >> 3, k = tid & 7;
  int wb = (n * K_ + k) * 64;
  float wxx[64];
  #pragma unroll
  for (int c = 0; c < 64; ++c) wxx[c] = Wxx[wb + c];
  float wxu[8], bxr[8];
  #pragma unroll
  for (int h = 0; h < 8; ++h){
    wxu[h] = Wxu[(n * K_ + k) * 8 + h];
    bxr[h] = bx [(n * K_ + k) * 8 + h];
  }
  for (int t = t0; t < t0 + 25; ++t){
    int bt = b * T_ + t;
    const float* xrow = X + (size_t)bt * 256 + n * 8;
    float xo[8], xc[8];
    #pragma unroll
    for (int h = 0; h < 8; ++h) xc[h] = xrow[h];
    if (t > 0){
      #pragma unroll
      for (int h = 0; h < 8; ++h) xo[h] = xrow[h - 256];
    } else {
      #pragma unroll
      for (int h = 0; h < 8; ++h) xo[h] = 0.f;
    }
    float u = U[bt * N_ + n];
    float s = 0.f;
    #pragma unroll
    for (int h = 0; h < 8; ++h){
      float xe = xo[h] + wxu[h] * u + bxr[h];
      #pragma unroll
      for (int j = 0; j < 8; ++j) xe += wxx[h * 8 + j] * xo[j];
      float d = xe - xc[h];
      s += d * d;
    }
    logB[(size_t)bt * 256 + tid] = -s;
  }
}

// log_A row k=q (max-subtraction form, used by final_kernel):
__device__ __forceinline__ void la_row_reg(const float (&wz)[64], const float (&wxu)[8],
                                           const float (&bxr)[8], const float (&xp)[8],
                                           float u, float itemp, float (&a)[8]){
  #pragma unroll
  for (int j = 0; j < 8; ++j){
    float x = bxr[j] + wxu[j] * u;
    #pragma unroll
    for (int h = 0; h < 8; ++h) x += wz[j * 8 + h] * xp[h];
    a[j] = x * itemp;
  }
  #pragma unroll
  for (int j = 0; j < 8; ++j){
    float mj = bmax8(a[j]);
    float ej = __expf(a[j] - mj);
    float sj = bsum8(ej);
    a[j] -= mj + __logf(sj);
  }
}

// log_A row k=q, fast no-max form (validated: absmax 0.0 in R3/R6 benches).
__device__ __forceinline__ void la_row_fast(const f32x2 (&wz2)[32], const float (&wxu)[8],
                                            const float (&bxr)[8],
                                            f32x2 xv0, f32x2 xv1, f32x2 xv2, f32x2 xv3,
                                            float u, float itemp, float (&a)[8]){
  #pragma unroll
  for (int j = 0; j < 8; ++j){
    f32x2 ac = {bxr[j] + wxu[j] * u, 0.f};
    ac = PKFMA(wz2[j * 4 + 0], xv0, ac);
    ac = PKFMA(wz2[j * 4 + 1], xv1, ac);
    ac = PKFMA(wz2[j * 4 + 2], xv2, ac);
    ac = PKFMA(wz2[j * 4 + 3], xv3, ac);
    a[j] = (ac.x + ac.y) * itemp;
  }
  #pragma unroll
  for (int j = 0; j < 8; ++j){
    float ej = __expf(a[j]);
    float sj = bsum8(ej);
    a[j] -= __logf(sj + 1e-33f);
  }
}

// ---------------- phase 1: chunk transition-matrix products ----------------
__global__ __launch_bounds__(256, 2)
void chunkmat_kernel(const float* __restrict__ X, const float* __restrict__ U,
                     const float* __restrict__ logB, const float* __restrict__ Wzx,
                     const float* __restrict__ Wxu, const float* __restrict__ bx,
                     const void* tempP, float* __restrict__ Mbuf){
  int l = threadIdx.x & 63;
  int unit = blockIdx.x * 4 + (threadIdx.x >> 6);  // < B_*N_*C_ = 20480
  int ci = unit % C_;
  int bn = unit / C_;
  int n = bn & (N_ - 1);
  int b = bn >> 5;
  int r = l & 7;
  float itemp = 1.f / decode_scalar(tempP);
  f32x2 wz2[32];
  const f32x2* wzr = (const f32x2*)(Wzx + (n * K_ + r) * 64);
  #pragma unroll
  for (int c = 0; c < 32; ++c) wz2[c] = wzr[c];
  float wxu[8], bxr[8];
  #pragma unroll
  for (int j = 0; j < 8; ++j){
    wxu[j] = Wxu[(n * K_ + r) * 8 + j];
    bxr[j] = bx [(n * K_ + r) * 8 + j];
  }
  int tlo = ci * L_ + 1;
  int thi = min(ci * L_ + L_, T_ - 1);
  float M = (r == (l >> 3)) ? 0.f : -1e30f;
  float pxp[8], pu, plb;
  {
    const float* xr = X + (size_t)(b * T_ + tlo - 1) * 256 + n * 8;
    #pragma unroll
    for (int h = 0; h < 8; ++h) pxp[h] = xr[h];
    pu  = U[(b * T_ + tlo) * N_ + n];
    plb = logB[(size_t)(b * T_ + tlo) * 256 + n * 8 + r];
  }
  for (int tau = tlo; tau <= thi; ++tau){
    f32x2 xv0 = {pxp[0], pxp[1]}, xv1 = {pxp[2], pxp[3]};
    f32x2 xv2 = {pxp[4], pxp[5]}, xv3 = {pxp[6], pxp[7]};
    float u = pu, lbr = plb;
    if (tau + 1 <= thi){
      const float* xr = X + (size_t)(b * T_ + tau) * 256 + n * 8;
      #pragma unroll
      for (int h = 0; h < 8; ++h) pxp[h] = xr[h];
      pu  = U[(b * T_ + tau + 1) * N_ + n];
      plb = logB[(size_t)(b * T_ + tau + 1) * 256 + n * 8 + r];
    }
    float a[8];
    la_row_fast(wz2, wxu, bxr, xv0, xv1, xv2, xv3, u, itemp, a);
    float tm[8];
    float mx = -3.4e38f;
    #pragma unroll
    for (int m = 0; m < 8; ++m){
      float Mg = __shfl(M, (l & 56) | m);
      tm[m] = a[m] + Mg;
      mx = fmaxf(mx, tm[m]);
    }
    float se = 0.f;
    #pragma unroll
    for (int m = 0; m < 8; ++m) se += __expf(tm[m] - mx);
    float Mn = lbr + mx + __logf(se);
    float gm = Mn;
    #pragma unroll
    for (int msk = 1; msk < 64; msk <<= 1) gm = fmaxf(gm, __shfl_xor(gm, msk));
    M = Mn - gm;
  }
  Mbuf[((size_t)(ci * B_ + b) * N_ + n) * 64 + l] = M;
}

// ---------------- phase 2: serial chunk-boundary scan (tiny) ----------------
__global__ __launch_bounds__(256, 1)
void boundary_kernel(const float* __restrict__ logB, const float* __restrict__ Zinit,
                     const float* __restrict__ Mbuf, float* __restrict__ fB,
                     float* __restrict__ gB, float* __restrict__ fwdp,
                     float* __restrict__ bwdp){
  int dir = blockIdx.x & 1, b = blockIdx.x >> 1;
  int tid = threadIdx.x;
  int n = tid >> 3, q = tid & 7;
  int gb = (tid & 63) & 56;
  if (dir == 0){
    float v = Zinit[tid] + logB[(size_t)(b * T_) * 256 + tid];
    float m = bmax8(v); float e = __expf(v - m); float ss = bsum8(e);
    float p = v - m - __logf(ss);
    fwdp[(size_t)(b * T_) * 256 + tid] = p;
    fB[((size_t)(0 * B_ + b) * N_ + n) * 8 + q] = p;
    float prev[8];
    #pragma unroll
    for (int j = 0; j < 8; ++j) prev[j] = __shfl(p, gb + j);
    for (int ci = 0; ci < C_ - 1; ++ci){
      const float* mrow = Mbuf + ((size_t)(ci * B_ + b) * N_ + n) * 64;
      float tm[8]; float mx = -3.4e38f;
      #pragma unroll
      for (int c = 0; c < 8; ++c){ tm[c] = mrow[(c << 3) + q] + prev[c]; mx = fmaxf(mx, tm[c]); }
      float se = 0.f;
      #pragma unroll
      for (int c = 0; c < 8; ++c) se += __expf(tm[c] - mx);
      float val = mx + __logf(se);
      float m2 = bmax8(val); float e2 = __expf(val - m2); float s2 = bsum8(e2);
      float p2 = val - m2 - __logf(s2);
      fB[((size_t)((ci + 1) * B_ + b) * N_ + n) * 8 + q] = p2;
      #pragma unroll
      for (int j = 0; j < 8; ++j) prev[j] = __shfl(p2, gb + j);
    }
  } else {
    bwdp[(size_t)(b * T_ + T_ - 1) * 256 + tid] = 0.f;
    gB[((size_t)((C_ - 1) * B_ + b) * N_ + n) * 8 + q] = 0.f;
    float g[8];
    #pragma unroll
    for (int j = 0; j < 8; ++j) g[j] = 0.f;
    for (int ci = C_ - 1; ci >= 1; --ci){
      const float* mcol = Mbuf + ((size_t)(ci * B_ + b) * N_ + n) * 64 + (q << 3);
      float tm[8]; float mx = -3.4e38f;
      #pragma unroll
      for (int k = 0; k < 8; ++k){ tm[k] = mcol[k] + g[k]; mx = fmaxf(mx, tm[k]); }
      float se = 0.f;
      #pragma unroll
      for (int k = 0; k < 8; ++k) se += __expf(tm[k] - mx);
      float val = mx + __logf(se);
      float m2 = bmax8(val); float e2 = __expf(val - m2); float s2 = bsum8(e2);
      float p2 = val - m2 - __logf(s2);
      gB[((size_t)((ci - 1) * B_ + b) * N_ + n) * 8 + q] = p2;
      #pragma unroll
      for (int k = 0; k < 8; ++k) g[k] = __shfl(p2, gb + k);
    }
  }
}

// ---------------- phase 3: within-chunk recursions (parallel over chunks) ----
__global__ __launch_bounds__(256, 2)
void chunkscan_kernel(const float* __restrict__ X, const float* __restrict__ U,
                      const float* __restrict__ logB, const float* __restrict__ Wzx,
                      const float* __restrict__ Wxu, const float* __restrict__ bx,
                      const float* __restrict__ fB, const float* __restrict__ gB,
                      const void* tempP, float* __restrict__ fwdp,
                      float* __restrict__ bwdp){
  int bid = blockIdx.x;
  int dir = bid & 1;
  int rest = bid >> 1;
  int ci = rest % C_;
  int b = rest / C_;
  int tid = threadIdx.x;
  int n = tid >> 3, q = tid & 7;
  int gb = (tid & 63) & 56;
  float itemp = 1.f / decode_scalar(tempP);
  f32x2 wz2[32];
  const f32x2* wzr = (const f32x2*)(Wzx + (n * K_ + q) * 64);
  #pragma unroll
  for (int c = 0; c < 32; ++c) wz2[c] = wzr[c];
  float wxu[8], bxr[8];
  #pragma unroll
  for (int j = 0; j < 8; ++j){
    wxu[j] = Wxu[(n * K_ + q) * 8 + j];
    bxr[j] = bx [(n * K_ + q) * 8 + j];
  }
  int tlo = ci * L_ + 1;
  int thi = min(ci * L_ + L_, T_ - 1);

  if (dir == 0){
    float p = fB[((size_t)(ci * B_ + b) * N_ + n) * 8 + q];
    float prev[8];
    #pragma unroll
    for (int j = 0; j < 8; ++j) prev[j] = __shfl(p, gb + j);
    float pxp[8], pu, plb;
    {
      const float* xr = X + (size_t)(b * T_ + tlo - 1) * 256 + n * 8;
      #pragma unroll
      for (int h = 0; h < 8; ++h) pxp[h] = xr[h];
      pu  = U[(b * T_ + tlo) * N_ + n];
      plb = logB[(size_t)(b * T_ + tlo) * 256 + tid];
    }
    for (int t = tlo; t <= thi; ++t){
      f32x2 xv0 = {pxp[0], pxp[1]}, xv1 = {pxp[2], pxp[3]};
      f32x2 xv2 = {pxp[4], pxp[5]}, xv3 = {pxp[6], pxp[7]};
      float u = pu, lbq = plb;
      if (t + 1 <= thi){
        const float* xr = X + (size_t)(b * T_ + t) * 256 + n * 8;
        #pragma unroll
        for (int h = 0; h < 8; ++h) pxp[h] = xr[h];
        pu  = U[(b * T_ + t + 1) * N_ + n];
        plb = logB[(size_t)(b * T_ + t + 1) * 256 + tid];
      }
      float a[8];
      la_row_fast(wz2, wxu, bxr, xv0, xv1, xv2, xv3, u, itemp, a);
      float se = 0.f;
      #pragma unroll
      for (int j = 0; j < 8; ++j) se += __expf(a[j] + prev[j]);
      float val = lbq + __logf(se + 1e-33f);
      float e2 = __expf(val); float s2 = bsum8(e2);
      float p2 = val - __logf(s2 + 1e-33f);
      fwdp[(size_t)(b * T_ + t) * 256 + tid] = p2;
      #pragma unroll
      for (int j = 0; j < 8; ++j) prev[j] = __shfl(p2, gb + j);
    }
  } else {
    float p = gB[((size_t)(ci * B_ + b) * N_ + n) * 8 + q];
    float nxt[8];
    #pragma unroll
    for (int j = 0; j < 8; ++j) nxt[j] = __shfl(p, gb + j);
    float pxp[8], pu, plb;
    {
      const float* xr = X + (size_t)(b * T_ + thi - 1) * 256 + n * 8;
      #pragma unroll
      for (int h = 0; h < 8; ++h) pxp[h] = xr[h];
      pu  = U[(b * T_ + thi) * N_ + n];
      plb = logB[(size_t)(b * T_ + thi) * 256 + tid];
    }
    for (int tau = thi; tau >= tlo; --tau){
      f32x2 xv0 = {pxp[0], pxp[1]}, xv1 = {pxp[2], pxp[3]};
      f32x2 xv2 = {pxp[4], pxp[5]}, xv3 = {pxp[6], pxp[7]};
      float u = pu, lbq = plb;
      if (tau - 1 >= tlo){
        const float* xr = X + (size_t)(b * T_ + tau - 2) * 256 + n * 8;
        #pragma unroll
        for (int h = 0; h < 8; ++h) pxp[h] = xr[h];
        pu  = U[(b * T_ + tau - 1) * N_ + n];
        plb = logB[(size_t)(b * T_ + tau - 1) * 256 + tid];
      }
      float a[8];
      la_row_fast(wz2, wxu, bxr, xv0, xv1, xv2, xv3, u, itemp, a);
      float nq = nxt[0];
      #pragma unroll
      for (int j = 1; j < 8; ++j) nq = (q == j) ? nxt[j] : nq;
      float out[8];
      #pragma unroll
      for (int j = 0; j < 8; ++j){
        float ej = __expf(nq + a[j] + lbq);
        float sj = bsum8(ej);
        out[j] = __logf(sj + 1e-33f);
      }
      float se = 0.f;
      #pragma unroll
      for (int j = 0; j < 8; ++j) se += __expf(out[j]);
      float lse = __logf(se + 1e-33f);
      #pragma unroll
      for (int j = 0; j < 8; ++j) nxt[j] = out[j] - lse;
      float own = nxt[0];
      #pragma unroll
      for (int j = 1; j < 8; ++j) own = (q == j) ? nxt[j] : own;
      bwdp[(size_t)(b * T_ + tau - 1) * 256 + tid] = own;
    }
  }
}

// ---------------- final reductions ----------------
__global__ __launch_bounds__(256, 2)
void final_kernel(const float* __restrict__ X, const float* __restrict__ U,
                  const float* __restrict__ logB, const float* __restrict__ fwdp,
                  const float* __restrict__ bwdp, const float* __restrict__ Wzx,
                  const float* __restrict__ Wxu, const float* __restrict__ bx,
                  const float* __restrict__ Zinit, const float* __restrict__ Wyx,
                  const float* __restrict__ Wyxb, const float* __restrict__ Y,
                  const void* tempP, double* __restrict__ acc){
  int b  = blockIdx.y;
  int t0 = blockIdx.x * 25;
  int tid = threadIdx.x;
  int n = tid >> 3, q = tid & 7;
  int lane = tid & 63, wid = tid >> 6;
  float itemp = 1.f / decode_scalar(tempP);
  float wz[64];
  int wb0 = (n * K_ + q) * 64;
  #pragma unroll
  for (int c = 0; c < 64; ++c) wz[c] = Wzx[wb0 + c];
  float wxu[8], bxr[8];
  #pragma unroll
  for (int j = 0; j < 8; ++j){
    wxu[j] = Wxu[(n * K_ + q) * 8 + j];
    bxr[j] = bx [(n * K_ + q) * 8 + j];
  }
  float wy = Wyx[tid];
  __shared__ float lys[4];
  __shared__ float red[4][4];
  float aY = 0.f, aI = 0.f, aS = 0.f, aG = 0.f;
  for (int t = t0; t < t0 + 25; ++t){
    size_t bt  = (size_t)b * T_ + t;
    size_t idx = bt * 256 + tid;
    float f  = fwdp[idx];
    float bw = bwdp[idx];
    float s  = f + bw;
    float m  = bmax8(s); float e = __expf(s - m); float ss = bsum8(e);
    float g1 = s - m - __logf(ss);
    aG += g1;
    if (t == 0){
      aI += __expf(g1) * (logB[idx] + Zinit[tid]);
    } else {
      float xp[8];
      const float* xr = X + (bt - 1) * 256 + n * 8;
      #pragma unroll
      for (int h = 0; h < 8; ++h) xp[h] = xr[h];
      float uu = U[bt * N_ + n];
      float a[8];
      la_row_reg(wz, wxu, bxr, xp, uu, itemp, a);
      float lbq = logB[idx];
      float fp[8];
      const float* frow = fwdp + (bt - 1) * 256 + n * 8;
      #pragma unroll
      for (int j = 0; j < 8; ++j) fp[j] = frow[j];
      float rr[8];
      float mx = -3.4e38f;
      #pragma unroll
      for (int j = 0; j < 8; ++j){ rr[j] = fp[j] + bw + a[j] + lbq; mx = fmaxf(mx, rr[j]); }
      mx = bmax8(mx);
      float se = 0.f;
      #pragma unroll
      for (int j = 0; j < 8; ++j) se += __expf(rr[j] - mx);
      se = bsum8(se);
      float lse = mx + __logf(se);
      const float* lbrow = logB + bt * 256 + n * 8;
      float part = 0.f;
      #pragma unroll
      for (int j = 0; j < 8; ++j) part += __expf(rr[j] - lse) * (a[j] + lbrow[j]);
      aS += part;
    }
    float yv = X[bt * 256 + tid] * wy;
    #pragma unroll
    for (int msk = 1; msk < 64; msk <<= 1) yv += __shfl_xor(yv, msk);
    if (lane == 0) lys[wid] = yv;
    __syncthreads();
    if (tid == 0){
      float ye = lys[0] + lys[1] + lys[2] + lys[3] + Wyxb[0] - Y[bt];
      aY -= ye * ye;
    }
    __syncthreads();
  }
  #pragma unroll
  for (int r = 0; r < 4; ++r){
    float v = (r == 0) ? aY : (r == 1) ? aI : (r == 2) ? aS : aG;
    #pragma unroll
    for (int msk = 1; msk < 64; msk <<= 1) v += __shfl_xor(v, msk);
    if (lane == 0) red[r][wid] = v;
  }
  __syncthreads();
  if (tid < 4){
    double v = (double)red[tid][0] + (double)red[tid][1]
             + (double)red[tid][2] + (double)red[tid][3];
    atomicAdd(&acc[tid], v);
  }
}

__global__ void out_kernel(const double* __restrict__ acc, float* __restrict__ out){
  int i = threadIdx.x;
  if (i == 0) out[0] = (float)acc[0];
  if (i == 1) out[1] = (float)acc[1];
  if (i == 2) out[2] = (float)acc[2];
  if (i == 3) out[3] = (float)(acc[3] / (double)K_);
}

extern "C" void kernel_launch(void* const* d_in, const int* in_sizes, int n_in,
                              void* d_out, int out_size, void* d_ws, size_t ws_size,
                              hipStream_t stream){
  const float* Y       = (const float*)d_in[0];
  const float* U_raw   = (const float*)d_in[1];
  const float* C_syn   = (const float*)d_in[2];
  const float* U_scale = (const float*)d_in[3];
  const float* Z_init  = (const float*)d_in[4];
  const float* W_zx    = (const float*)d_in[5];
  const float* W_xx    = (const float*)d_in[6];
  const float* W_xu    = (const float*)d_in[7];
  const float* b_x     = (const float*)d_in[8];
  const float* W_yx_w  = (const float*)d_in[9];
  const float* W_yx_b  = (const float*)d_in[10];
  const float* Wih_f   = (const float*)d_in[11];
  const float* Whh_f   = (const float*)d_in[12];
  const float* bih_f   = (const float*)d_in[13];
  const float* bhh_f   = (const float*)d_in[14];
  const float* Wih_b   = (const float*)d_in[15];
  const float* Whh_b   = (const float*)d_in[16];
  const float* bih_b   = (const float*)d_in[17];
  const float* bhh_b   = (const float*)d_in[18];
  const float* enc_W   = (const float*)d_in[19];
  const float* enc_b   = (const float*)d_in[20];
  const void*  tempP   = d_in[21];

  char* ws = (char*)d_ws;
  size_t off = 0;
  auto alloc = [&](size_t elems) -> float* {
    float* p = (float*)(ws + off);
    off += elems * sizeof(float);
    off = (off + 255) & ~(size_t)255;
    return p;
  };
  float* U    = alloc((size_t)B_ * T_ * N_);        //  2.05 MB
  float* giF  = alloc((size_t)T_ * B_ * G3_);       // 24.58 MB
  float* giB  = alloc((size_t)T_ * B_ * G3_);       // 24.58 MB
  float* ht   = alloc((size_t)T_ * B_ * 256);       // 16.38 MB
  float* X    = alloc((size_t)B_ * T_ * 256);       // 16.38 MB
  float* logB = alloc((size_t)B_ * T_ * 256);       // 16.38 MB
  float* fwdp = alloc((size_t)B_ * T_ * 256);       // 16.38 MB
  float* bwdp = alloc((size_t)B_ * T_ * 256);       // 16.38 MB
  double* acc = (double*)(ws + off);                // 32 B    (total ~133.2 MB)

  // scan scratch aliased into giF/giB (dead after gru_kernel):
  float* Mbuf = giF;                                   // 5.24 MB
  float* fB   = giF + (size_t)C_ * B_ * N_ * 64;       // 0.65 MB
  float* gB   = fB + (size_t)C_ * B_ * N_ * 8;         // 0.65 MB (all < 24.58 MB)

  hipMemsetAsync(acc, 0, 4 * sizeof(double), stream);
  u_kernel   <<<B_ * T_ / 8, 256, 0, stream>>>(U_raw, U_scale, C_syn, U);
  gi_kernel  <<<B_ * T_ / 64, G3_, 0, stream>>>(Y, U, Wih_f, bih_f, Wih_b, bih_b, giF, giB);
  gru_kernel <<<32, 512, 0, stream>>>(Whh_f, bhh_f, Whh_b, bhh_b, giF, giB, ht);
  x_kernel   <<<B_ * T_ / 8, 256, 0, stream>>>(ht, enc_W, enc_b, X);
  logB_kernel<<<dim3(40, 16), 256, 0, stream>>>(X, U, W_xx, W_xu, b_x, logB);
  chunkmat_kernel<<<B_ * N_ * C_ / 4, 256, 0, stream>>>(X, U, logB, W_zx, W_xu, b_x,
                                                        tempP, Mbuf);
  boundary_kernel<<<32, 256, 0, stream>>>(logB, Z_init, Mbuf, fB, gB, fwdp, bwdp);
  chunkscan_kernel<<<2 * C_ * B_, 256, 0, stream>>>(X, U, logB, W_zx, W_xu, b_x,
                                                    fB, gB, tempP, fwdp, bwdp);
  final_kernel<<<dim3(40, 16), 256, 0, stream>>>(X, U, logB, fwdp, bwdp, W_zx, W_xu, b_x,
                                                 Z_init, W_yx_w, W_yx_b, Y, tempP, acc);
  out_kernel <<<1, 64, 0, stream>>>(acc, (float*)d_out);
}